// Round 8
// baseline (235.406 us; speedup 1.0000x reference)
//
#include <hip/hip_runtime.h>

#define NSEQ   2048
#define HEADS  16
#define DIM    64
#define BATCH  2
#define SCALE  0.125f      // 1/sqrt(64)

// Workspace: tree nodes, global index g in [NSEQ, 2*NSEQ-2), slot = g - NSEQ,
// layout [b][slot][h][d]. Invariant: parent(level_offset(j)+i) = level_offset(j+1)+i/2.
// Slot map: lvl1 0..1023, lvl2 1024.., lvl3 1536.., lvl4 1792.., lvl5 1920..,
// lvl6 1984.., lvl7 2016.., lvl8 2032.., lvl9 2040.., lvl10 2044,2045.
// After Vw: 32 unsigned counters (one per (b,h)) for the last-block pattern.
#define WSSLOTS 2048
#define WSELEMS ((size_t)BATCH * WSSLOTS * HEADS * DIM)
#define ROWF4   (DIM / 4)              // 16 float4 per row
#define HSTRIDE (HEADS * ROWF4)        // float4 stride between rows (n or slot)

__device__ __forceinline__ int level_offset(int j) {
    return (j == 0) ? 0 : (2 * NSEQ - ((2 * NSEQ) >> j));
}

__device__ __forceinline__ float dot4(float4 a, float4 b) {
    return a.x * b.x + a.y * b.y + a.z * b.z + a.w * b.w;
}

__device__ __forceinline__ void reduce3_16(float& a, float& b, float& c) {
#pragma unroll
    for (int m = 1; m < 16; m <<= 1) {
        a += __shfl_xor(a, m, 64);
        b += __shfl_xor(b, m, 64);
        c += __shfl_xor(c, m, 64);
    }
}

__device__ __forceinline__ void reduce6_16(float& a, float& b, float& c,
                                           float& d, float& e, float& f) {
#pragma unroll
    for (int m = 1; m < 16; m <<= 1) {
        a += __shfl_xor(a, m, 64);
        b += __shfl_xor(b, m, 64);
        c += __shfl_xor(c, m, 64);
        d += __shfl_xor(d, m, 64);
        e += __shfl_xor(e, m, 64);
        f += __shfl_xor(f, m, 64);
    }
}

// Parent = 3-way softmax mix of {mean, child0, child1}; 16 lanes / parent.
__device__ __forceinline__ void make_parent4(float4 k0, float4 k1, float4 v0, float4 v1,
                                             float4& kc, float4& vc) {
    float4 kp, vp;
    kp.x = 0.5f * (k0.x + k1.x); kp.y = 0.5f * (k0.y + k1.y);
    kp.z = 0.5f * (k0.z + k1.z); kp.w = 0.5f * (k0.w + k1.w);
    vp.x = 0.5f * (v0.x + v1.x); vp.y = 0.5f * (v0.y + v1.y);
    vp.z = 0.5f * (v0.z + v1.z); vp.w = 0.5f * (v0.w + v1.w);
    float ss = dot4(kp, kp), sa = dot4(kp, k0), sb = dot4(kp, k1);
    reduce3_16(ss, sa, sb);
    ss *= SCALE; sa *= SCALE; sb *= SCALE;
    float mx = fmaxf(ss, fmaxf(sa, sb));
    float es = __expf(ss - mx), ea = __expf(sa - mx), eb = __expf(sb - mx);
    float inv = 1.0f / (es + ea + eb + 1e-9f);
    es *= inv; ea *= inv; eb *= inv;
    kc.x = es * kp.x + ea * k0.x + eb * k1.x;
    kc.y = es * kp.y + ea * k0.y + eb * k1.y;
    kc.z = es * kp.z + ea * k0.z + eb * k1.z;
    kc.w = es * kp.w + ea * k0.w + eb * k1.w;
    vc.x = es * vp.x + ea * v0.x + eb * v1.x;
    vc.y = es * vp.y + ea * v0.y + eb * v1.y;
    vc.z = es * vp.z + ea * v0.z + eb * v1.z;
    vc.w = es * vp.w + ea * v0.w + eb * v1.w;
}

// Two independent sibling mixes with an interleaved 6-value butterfly (ILP).
__device__ __forceinline__ void make_parent_pair4(const float4* k, const float4* v,
                                                  float4& ka, float4& va,
                                                  float4& kb, float4& vb) {
    float4 kpa, vpa, kpb, vpb;
    kpa.x = 0.5f * (k[0].x + k[1].x); kpa.y = 0.5f * (k[0].y + k[1].y);
    kpa.z = 0.5f * (k[0].z + k[1].z); kpa.w = 0.5f * (k[0].w + k[1].w);
    vpa.x = 0.5f * (v[0].x + v[1].x); vpa.y = 0.5f * (v[0].y + v[1].y);
    vpa.z = 0.5f * (v[0].z + v[1].z); vpa.w = 0.5f * (v[0].w + v[1].w);
    kpb.x = 0.5f * (k[2].x + k[3].x); kpb.y = 0.5f * (k[2].y + k[3].y);
    kpb.z = 0.5f * (k[2].z + k[3].z); kpb.w = 0.5f * (k[2].w + k[3].w);
    vpb.x = 0.5f * (v[2].x + v[3].x); vpb.y = 0.5f * (v[2].y + v[3].y);
    vpb.z = 0.5f * (v[2].z + v[3].z); vpb.w = 0.5f * (v[2].w + v[3].w);
    float ssa = dot4(kpa, kpa), saa = dot4(kpa, k[0]), sba = dot4(kpa, k[1]);
    float ssb = dot4(kpb, kpb), sab = dot4(kpb, k[2]), sbb = dot4(kpb, k[3]);
    reduce6_16(ssa, saa, sba, ssb, sab, sbb);
    ssa *= SCALE; saa *= SCALE; sba *= SCALE;
    ssb *= SCALE; sab *= SCALE; sbb *= SCALE;
    float mxa = fmaxf(ssa, fmaxf(saa, sba));
    float mxb = fmaxf(ssb, fmaxf(sab, sbb));
    float esa = __expf(ssa - mxa), eaa = __expf(saa - mxa), eba = __expf(sba - mxa);
    float esb = __expf(ssb - mxb), eab = __expf(sab - mxb), ebb = __expf(sbb - mxb);
    float iva = 1.0f / (esa + eaa + eba + 1e-9f);
    float ivb = 1.0f / (esb + eab + ebb + 1e-9f);
    esa *= iva; eaa *= iva; eba *= iva;
    esb *= ivb; eab *= ivb; ebb *= ivb;
    ka.x = esa * kpa.x + eaa * k[0].x + eba * k[1].x;
    ka.y = esa * kpa.y + eaa * k[0].y + eba * k[1].y;
    ka.z = esa * kpa.z + eaa * k[0].z + eba * k[1].z;
    ka.w = esa * kpa.w + eaa * k[0].w + eba * k[1].w;
    va.x = esa * vpa.x + eaa * v[0].x + eba * v[1].x;
    va.y = esa * vpa.y + eaa * v[0].y + eba * v[1].y;
    va.z = esa * vpa.z + eaa * v[0].z + eba * v[1].z;
    va.w = esa * vpa.w + eaa * v[0].w + eba * v[1].w;
    kb.x = esb * kpb.x + eab * k[2].x + ebb * k[3].x;
    kb.y = esb * kpb.y + eab * k[2].y + ebb * k[3].y;
    kb.z = esb * kpb.z + eab * k[2].z + ebb * k[3].z;
    kb.w = esb * kpb.w + eab * k[2].w + ebb * k[3].w;
    vb.x = esb * vpb.x + eab * v[2].x + ebb * v[3].x;
    vb.y = esb * vpb.y + eab * v[2].y + ebb * v[3].y;
    vb.z = esb * vpb.z + eab * v[2].z + ebb * v[3].z;
    vb.w = esb * vpb.w + eab * v[2].w + ebb * v[3].w;
}

// 4-ary consolidation step: 4 child rows -> 2 parents (stored) + 1 grandparent.
__device__ __forceinline__ void quad_step(const float4* k, const float4* v,
                                          float4* Kw4, float4* Vw4,
                                          size_t pRow0, size_t gRow,   // float4 base offsets (+t)
                                          int t,
                                          float4& kg, float4& vg) {
    float4 ka, va, kb, vb;
    make_parent_pair4(k, v, ka, va, kb, vb);
    Kw4[pRow0 + t] = ka;            Vw4[pRow0 + t] = va;
    Kw4[pRow0 + HSTRIDE + t] = kb;  Vw4[pRow0 + HSTRIDE + t] = vb;
    make_parent4(ka, kb, va, vb, kg, vg);
    Kw4[gRow + t] = kg;             Vw4[gRow + t] = vg;
}

// ---- Kernel A: full tree. 1024 blocks = (b,h,chunk). Levels 1..6 per chunk;
// then the LAST block of each (b,h) (device-scope atomic counter + fences)
// computes levels 7..10 for that (b,h) — replaces the old 32-block tree_top
// launch (which ran at 12.5% CU occupancy plus a dispatch gap).
__global__ __launch_bounds__(256) void tree_fused(const float* __restrict__ K,
                                                  const float* __restrict__ V,
                                                  float* __restrict__ Kw,
                                                  float* __restrict__ Vw,
                                                  unsigned* __restrict__ cnt) {
    __shared__ float4 Kb[20 * ROWF4];   // rows [0,16): lvl2 ; rows [16,20): lvl4
    __shared__ float4 Vb[20 * ROWF4];
    __shared__ unsigned lastFlag;
    const float4* K4 = (const float4*)K;
    const float4* V4 = (const float4*)V;
    float4* Kw4 = (float4*)Kw;
    float4* Vw4 = (float4*)Vw;

    int bid = blockIdx.x;
    int c = bid & 31;
    int bh = bid >> 5;                 // 0..31 = (b<<4)|h
    int h = bh & 15;
    int b = bh >> 4;
    int lane = threadIdx.x & 63;
    int gg = (threadIdx.x >> 6) * 4 + (lane >> 4);   // group 0..15
    int t = lane & 15;

    size_t wsBase = (size_t)(b * WSSLOTS) * HSTRIDE + h * ROWF4;  // + slot*HSTRIDE + t

    // Round A: 16 groups, 4 leaves each -> lvl1 pair + lvl2 node
    {
        int n0 = c * 64 + 4 * gg;
        const float4* Kr = K4 + ((size_t)((b * NSEQ + n0) * HEADS + h)) * ROWF4;
        const float4* Vr = V4 + ((size_t)((b * NSEQ + n0) * HEADS + h)) * ROWF4;
        float4 k[4], v[4];
#pragma unroll
        for (int j = 0; j < 4; ++j) { k[j] = Kr[j * HSTRIDE + t]; v[j] = Vr[j * HSTRIDE + t]; }
        int s1 = c * 32 + 2 * gg;          // lvl1 slots s1, s1+1
        int s2 = 1024 + c * 16 + gg;       // lvl2 slot
        float4 kg, vg;
        quad_step(k, v, Kw4, Vw4, wsBase + (size_t)s1 * HSTRIDE,
                  wsBase + (size_t)s2 * HSTRIDE, t, kg, vg);
        Kb[gg * ROWF4 + t] = kg;  Vb[gg * ROWF4 + t] = vg;
    }
    __syncthreads();
    // Round B: groups 0..3, lvl2 rows -> lvl3 pair + lvl4 node
    if (gg < 4) {
        float4 k[4], v[4];
#pragma unroll
        for (int j = 0; j < 4; ++j) {
            k[j] = Kb[(4 * gg + j) * ROWF4 + t];
            v[j] = Vb[(4 * gg + j) * ROWF4 + t];
        }
        int s3 = 1536 + c * 8 + 2 * gg;
        int s4 = 1792 + c * 4 + gg;
        float4 kg, vg;
        quad_step(k, v, Kw4, Vw4, wsBase + (size_t)s3 * HSTRIDE,
                  wsBase + (size_t)s4 * HSTRIDE, t, kg, vg);
        Kb[(16 + gg) * ROWF4 + t] = kg;  Vb[(16 + gg) * ROWF4 + t] = vg;
    }
    __syncthreads();
    // Round C: group 0, lvl4 rows -> lvl5 pair + lvl6 node
    if (gg == 0) {
        float4 k[4], v[4];
#pragma unroll
        for (int j = 0; j < 4; ++j) {
            k[j] = Kb[(16 + j) * ROWF4 + t];
            v[j] = Vb[(16 + j) * ROWF4 + t];
        }
        int s5 = 1920 + c * 2;
        int s6 = 1984 + c;
        float4 kg, vg;
        quad_step(k, v, Kw4, Vw4, wsBase + (size_t)s5 * HSTRIDE,
                  wsBase + (size_t)s6 * HSTRIDE, t, kg, vg);
    }

    // ---- last-block election (release: stores -> fence -> syncthreads -> atomic)
    __threadfence();                      // make this block's ws stores device-visible
    __syncthreads();                      // all threads' fences happen-before the atomic
    if (threadIdx.x == 0)
        lastFlag = (atomicAdd(&cnt[bh], 1u) == 31u);
    __syncthreads();
    if (!lastFlag) return;
    __threadfence();                      // acquire: discard stale lines before reading peers' lvl6

    // ---- levels 7..10 for this (b,h), reusing LDS rows [0,8) for lvl8 nodes
    // Round D: groups 0..7: 4 lvl6 rows -> lvl7 pair + lvl8 node
    if (gg < 8) {
        float4 k[4], v[4];
#pragma unroll
        for (int j = 0; j < 4; ++j) {
            size_t r = wsBase + (size_t)(1984 + 4 * gg + j) * HSTRIDE + t;
            k[j] = Kw4[r]; v[j] = Vw4[r];
        }
        int s7 = 2016 + 2 * gg;
        int s8 = 2032 + gg;
        float4 kg, vg;
        quad_step(k, v, Kw4, Vw4, wsBase + (size_t)s7 * HSTRIDE,
                  wsBase + (size_t)s8 * HSTRIDE, t, kg, vg);
        Kb[gg * ROWF4 + t] = kg;  Vb[gg * ROWF4 + t] = vg;
    }
    __syncthreads();
    // Round E: groups 0..1: 4 lvl8 rows -> lvl9 pair + lvl10 node
    if (gg < 2) {
        float4 k[4], v[4];
#pragma unroll
        for (int j = 0; j < 4; ++j) {
            k[j] = Kb[(4 * gg + j) * ROWF4 + t];
            v[j] = Vb[(4 * gg + j) * ROWF4 + t];
        }
        int s9  = 2040 + 2 * gg;
        int s10 = 2044 + gg;
        float4 kg, vg;
        quad_step(k, v, Kw4, Vw4, wsBase + (size_t)s9 * HSTRIDE,
                  wsBase + (size_t)s10 * HSTRIDE, t, kg, vg);
    }
}

// ---- Kernel C: attention. One wave = 4 heads of one (b,n). 4096 blocks.
// Masked columns have weight exactly 0 -> skip their K/V loads, dots, and
// V-accumulation entirely (mask is wave-uniform: same n across the wave).
__global__ __launch_bounds__(256) void attn(const float* __restrict__ Q,
                                            const float* __restrict__ K,
                                            const float* __restrict__ V,
                                            const float* __restrict__ Kw,
                                            const float* __restrict__ Vw,
                                            float* __restrict__ out) {
    const float4* Q4 = (const float4*)Q;
    const float4* K4 = (const float4*)K;
    const float4* V4 = (const float4*)V;
    const float4* Kw4 = (const float4*)Kw;
    const float4* Vw4 = (const float4*)Vw;
    float4* O4 = (float4*)out;

    int bid = blockIdx.x;                              // 0..4095
    int vbid = ((bid & 7) << 9) | (bid >> 3);          // bijective XCD remap
    int w = vbid * 4 + (threadIdx.x >> 6);             // wave id over B*N*(H/4)
    int lane = threadIdx.x & 63;
    int g = lane >> 4;
    int t = lane & 15;
    int h = (w & 3) * 4 + g;
    int n = (w >> 2) & (NSEQ - 1);
    int b = w >> 13;

    int row0 = (b * NSEQ + n) * HSTRIDE;               // self leaf / Q / out
    int row1 = (b * NSEQ + (n ^ 1)) * HSTRIDE;         // sibling leaf
    int rowt[10];
#pragma unroll
    for (int l = 2; l < 12; ++l) {
        int j = l - 1;
        int slot = level_offset(j) - NSEQ + ((n >> j) ^ 1);
        rowt[l - 2] = (b * WSSLOTS + slot) * HSTRIDE;
    }
    int hoff = h * ROWF4 + t;

    // column l active iff l==0 or bit (l-1) of n set (wave-uniform)
    unsigned active = 1u | (((unsigned)n & 0x7FFu) << 1);

    float4 q4 = Q4[row0 + hoff];

    float4 k[12], v[12];
    float s[12];
    k[0] = K4[row0 + hoff];
    v[0] = V4[row0 + hoff];
    if (active & 2u) { k[1] = K4[row1 + hoff]; v[1] = V4[row1 + hoff]; }
#pragma unroll
    for (int l = 2; l < 12; ++l) {
        if (active & (1u << l)) {
            k[l] = Kw4[rowt[l - 2] + hoff];
            v[l] = Vw4[rowt[l - 2] + hoff];
        }
    }
    s[0] = dot4(q4, k[0]);
#pragma unroll
    for (int l = 1; l < 12; ++l)
        s[l] = (active & (1u << l)) ? dot4(q4, k[l]) : 0.f;

#pragma unroll
    for (int m = 1; m < 16; m <<= 1) {
#pragma unroll
        for (int l = 0; l < 12; ++l) s[l] += __shfl_xor(s[l], m, 64);
    }

    float mx = -3.402823466e+38f;
#pragma unroll
    for (int l = 0; l < 12; ++l) {
        s[l] *= SCALE;
        if (active & (1u << l)) mx = fmaxf(mx, s[l]);
    }
    float sum = 0.f;
#pragma unroll
    for (int l = 0; l < 12; ++l) {
        float e = (active & (1u << l)) ? __expf(s[l] - mx) : 0.f;
        s[l] = e;
        sum += e;
    }
    float inv = 1.0f / sum;

    float4 o = make_float4(0.f, 0.f, 0.f, 0.f);
    o.x += s[0] * v[0].x; o.y += s[0] * v[0].y;
    o.z += s[0] * v[0].z; o.w += s[0] * v[0].w;
#pragma unroll
    for (int l = 1; l < 12; ++l) {
        if (active & (1u << l)) {
            o.x += s[l] * v[l].x; o.y += s[l] * v[l].y;
            o.z += s[l] * v[l].z; o.w += s[l] * v[l].w;
        }
    }
    O4[row0 + hoff] = make_float4(o.x * inv, o.y * inv, o.z * inv, o.w * inv);
}

extern "C" void kernel_launch(void* const* d_in, const int* in_sizes, int n_in,
                              void* d_out, int out_size, void* d_ws, size_t ws_size,
                              hipStream_t stream) {
    const float* Q = (const float*)d_in[0];
    const float* K = (const float*)d_in[1];
    const float* V = (const float*)d_in[2];
    float* out = (float*)d_out;
    float* Kw = (float*)d_ws;              // 16.78 MiB
    float* Vw = Kw + WSELEMS;              // 16.78 MiB
    unsigned* cnt = (unsigned*)(Vw + WSELEMS);  // 32 counters (ws is 0xAA-poisoned)

    hipMemsetAsync(cnt, 0, BATCH * HEADS * sizeof(unsigned), stream);
    tree_fused<<<1024, 256, 0, stream>>>(K, V, Kw, Vw, cnt);
    attn<<<(BATCH * NSEQ * (HEADS / 4)) / 4, 256, 0, stream>>>(Q, K, V, Kw, Vw, out);
}

// Round 9
// 117.669 us; speedup vs baseline: 2.0006x; 2.0006x over previous
//
#include <hip/hip_runtime.h>

#define NSEQ   2048
#define HEADS  16
#define DIM    64
#define BATCH  2
#define SCALE  0.125f      // 1/sqrt(64)

// Workspace: tree nodes, global index g in [NSEQ, 2*NSEQ-2), slot = g - NSEQ,
// layout [b][slot][h][d]. Invariant: parent(level_offset(j)+i) = level_offset(j+1)+i/2.
// Slot map: lvl1 0..1023, lvl2 1024.., lvl3 1536.., lvl4 1792.., lvl5 1920..,
// lvl6 1984.., lvl7 2016.., lvl8 2032.., lvl9 2040.., lvl10 2044,2045.
// NOTE (R8 lesson): do NOT fuse tree_top via last-block + __threadfence();
// per-block device-scope fences cost ~100 µs at 1024 blocks on MI355X.
// The kernel-launch boundary is the cheap cross-XCD coherence point.
#define WSSLOTS 2048
#define WSELEMS ((size_t)BATCH * WSSLOTS * HEADS * DIM)
#define ROWF4   (DIM / 4)              // 16 float4 per row
#define HSTRIDE (HEADS * ROWF4)        // float4 stride between rows (n or slot)

__device__ __forceinline__ int level_offset(int j) {
    return (j == 0) ? 0 : (2 * NSEQ - ((2 * NSEQ) >> j));
}

__device__ __forceinline__ float dot4(float4 a, float4 b) {
    return a.x * b.x + a.y * b.y + a.z * b.z + a.w * b.w;
}

__device__ __forceinline__ void reduce3_16(float& a, float& b, float& c) {
#pragma unroll
    for (int m = 1; m < 16; m <<= 1) {
        a += __shfl_xor(a, m, 64);
        b += __shfl_xor(b, m, 64);
        c += __shfl_xor(c, m, 64);
    }
}

__device__ __forceinline__ void reduce6_16(float& a, float& b, float& c,
                                           float& d, float& e, float& f) {
#pragma unroll
    for (int m = 1; m < 16; m <<= 1) {
        a += __shfl_xor(a, m, 64);
        b += __shfl_xor(b, m, 64);
        c += __shfl_xor(c, m, 64);
        d += __shfl_xor(d, m, 64);
        e += __shfl_xor(e, m, 64);
        f += __shfl_xor(f, m, 64);
    }
}

// Parent = 3-way softmax mix of {mean, child0, child1}; 16 lanes / parent.
__device__ __forceinline__ void make_parent4(float4 k0, float4 k1, float4 v0, float4 v1,
                                             float4& kc, float4& vc) {
    float4 kp, vp;
    kp.x = 0.5f * (k0.x + k1.x); kp.y = 0.5f * (k0.y + k1.y);
    kp.z = 0.5f * (k0.z + k1.z); kp.w = 0.5f * (k0.w + k1.w);
    vp.x = 0.5f * (v0.x + v1.x); vp.y = 0.5f * (v0.y + v1.y);
    vp.z = 0.5f * (v0.z + v1.z); vp.w = 0.5f * (v0.w + v1.w);
    float ss = dot4(kp, kp), sa = dot4(kp, k0), sb = dot4(kp, k1);
    reduce3_16(ss, sa, sb);
    ss *= SCALE; sa *= SCALE; sb *= SCALE;
    float mx = fmaxf(ss, fmaxf(sa, sb));
    float es = __expf(ss - mx), ea = __expf(sa - mx), eb = __expf(sb - mx);
    float inv = 1.0f / (es + ea + eb + 1e-9f);
    es *= inv; ea *= inv; eb *= inv;
    kc.x = es * kp.x + ea * k0.x + eb * k1.x;
    kc.y = es * kp.y + ea * k0.y + eb * k1.y;
    kc.z = es * kp.z + ea * k0.z + eb * k1.z;
    kc.w = es * kp.w + ea * k0.w + eb * k1.w;
    vc.x = es * vp.x + ea * v0.x + eb * v1.x;
    vc.y = es * vp.y + ea * v0.y + eb * v1.y;
    vc.z = es * vp.z + ea * v0.z + eb * v1.z;
    vc.w = es * vp.w + ea * v0.w + eb * v1.w;
}

// Two independent sibling mixes with an interleaved 6-value butterfly (ILP).
__device__ __forceinline__ void make_parent_pair4(const float4* k, const float4* v,
                                                  float4& ka, float4& va,
                                                  float4& kb, float4& vb) {
    float4 kpa, vpa, kpb, vpb;
    kpa.x = 0.5f * (k[0].x + k[1].x); kpa.y = 0.5f * (k[0].y + k[1].y);
    kpa.z = 0.5f * (k[0].z + k[1].z); kpa.w = 0.5f * (k[0].w + k[1].w);
    vpa.x = 0.5f * (v[0].x + v[1].x); vpa.y = 0.5f * (v[0].y + v[1].y);
    vpa.z = 0.5f * (v[0].z + v[1].z); vpa.w = 0.5f * (v[0].w + v[1].w);
    kpb.x = 0.5f * (k[2].x + k[3].x); kpb.y = 0.5f * (k[2].y + k[3].y);
    kpb.z = 0.5f * (k[2].z + k[3].z); kpb.w = 0.5f * (k[2].w + k[3].w);
    vpb.x = 0.5f * (v[2].x + v[3].x); vpb.y = 0.5f * (v[2].y + v[3].y);
    vpb.z = 0.5f * (v[2].z + v[3].z); vpb.w = 0.5f * (v[2].w + v[3].w);
    float ssa = dot4(kpa, kpa), saa = dot4(kpa, k[0]), sba = dot4(kpa, k[1]);
    float ssb = dot4(kpb, kpb), sab = dot4(kpb, k[2]), sbb = dot4(kpb, k[3]);
    reduce6_16(ssa, saa, sba, ssb, sab, sbb);
    ssa *= SCALE; saa *= SCALE; sba *= SCALE;
    ssb *= SCALE; sab *= SCALE; sbb *= SCALE;
    float mxa = fmaxf(ssa, fmaxf(saa, sba));
    float mxb = fmaxf(ssb, fmaxf(sab, sbb));
    float esa = __expf(ssa - mxa), eaa = __expf(saa - mxa), eba = __expf(sba - mxa);
    float esb = __expf(ssb - mxb), eab = __expf(sab - mxb), ebb = __expf(sbb - mxb);
    float iva = 1.0f / (esa + eaa + eba + 1e-9f);
    float ivb = 1.0f / (esb + eab + ebb + 1e-9f);
    esa *= iva; eaa *= iva; eba *= iva;
    esb *= ivb; eab *= ivb; ebb *= ivb;
    ka.x = esa * kpa.x + eaa * k[0].x + eba * k[1].x;
    ka.y = esa * kpa.y + eaa * k[0].y + eba * k[1].y;
    ka.z = esa * kpa.z + eaa * k[0].z + eba * k[1].z;
    ka.w = esa * kpa.w + eaa * k[0].w + eba * k[1].w;
    va.x = esa * vpa.x + eaa * v[0].x + eba * v[1].x;
    va.y = esa * vpa.y + eaa * v[0].y + eba * v[1].y;
    va.z = esa * vpa.z + eaa * v[0].z + eba * v[1].z;
    va.w = esa * vpa.w + eaa * v[0].w + eba * v[1].w;
    kb.x = esb * kpb.x + eab * k[2].x + ebb * k[3].x;
    kb.y = esb * kpb.y + eab * k[2].y + ebb * k[3].y;
    kb.z = esb * kpb.z + eab * k[2].z + ebb * k[3].z;
    kb.w = esb * kpb.w + eab * k[2].w + ebb * k[3].w;
    vb.x = esb * vpb.x + eab * v[2].x + ebb * v[3].x;
    vb.y = esb * vpb.y + eab * v[2].y + ebb * v[3].y;
    vb.z = esb * vpb.z + eab * v[2].z + ebb * v[3].z;
    vb.w = esb * vpb.w + eab * v[2].w + ebb * v[3].w;
}

// 4-ary consolidation step: 4 child rows -> 2 parents (stored) + 1 grandparent.
__device__ __forceinline__ void quad_step(const float4* k, const float4* v,
                                          float4* Kw4, float4* Vw4,
                                          size_t pRow0, size_t gRow,   // float4 base offsets (+t)
                                          int t,
                                          float4& kg, float4& vg) {
    float4 ka, va, kb, vb;
    make_parent_pair4(k, v, ka, va, kb, vb);
    Kw4[pRow0 + t] = ka;            Vw4[pRow0 + t] = va;
    Kw4[pRow0 + HSTRIDE + t] = kb;  Vw4[pRow0 + HSTRIDE + t] = vb;
    make_parent4(ka, kb, va, vb, kg, vg);
    Kw4[gRow + t] = kg;             Vw4[gRow + t] = vg;
}

// ---- Kernel A: tree levels 1..6 for one 64-leaf chunk. 1024 blocks (b,h,c).
// 3 rounds of 4-ary consolidation, 2 barriers.
__global__ __launch_bounds__(256) void tree_low(const float* __restrict__ K,
                                                const float* __restrict__ V,
                                                float* __restrict__ Kw,
                                                float* __restrict__ Vw) {
    __shared__ float4 Kb[20 * ROWF4];   // rows [0,16): lvl2 ; rows [16,20): lvl4
    __shared__ float4 Vb[20 * ROWF4];
    const float4* K4 = (const float4*)K;
    const float4* V4 = (const float4*)V;
    float4* Kw4 = (float4*)Kw;
    float4* Vw4 = (float4*)Vw;

    int bid = blockIdx.x;
    int c = bid & 31;
    int h = (bid >> 5) & 15;
    int b = bid >> 9;
    int lane = threadIdx.x & 63;
    int gg = (threadIdx.x >> 6) * 4 + (lane >> 4);   // group 0..15
    int t = lane & 15;

    size_t wsBase = (size_t)(b * WSSLOTS) * HSTRIDE + h * ROWF4;  // + slot*HSTRIDE + t

    // Round A: 16 groups, 4 leaves each -> lvl1 pair + lvl2 node
    {
        int n0 = c * 64 + 4 * gg;
        const float4* Kr = K4 + ((size_t)((b * NSEQ + n0) * HEADS + h)) * ROWF4;
        const float4* Vr = V4 + ((size_t)((b * NSEQ + n0) * HEADS + h)) * ROWF4;
        float4 k[4], v[4];
#pragma unroll
        for (int j = 0; j < 4; ++j) { k[j] = Kr[j * HSTRIDE + t]; v[j] = Vr[j * HSTRIDE + t]; }
        int s1 = c * 32 + 2 * gg;          // lvl1 slots s1, s1+1
        int s2 = 1024 + c * 16 + gg;       // lvl2 slot
        float4 kg, vg;
        quad_step(k, v, Kw4, Vw4, wsBase + (size_t)s1 * HSTRIDE,
                  wsBase + (size_t)s2 * HSTRIDE, t, kg, vg);
        Kb[gg * ROWF4 + t] = kg;  Vb[gg * ROWF4 + t] = vg;
    }
    __syncthreads();
    // Round B: groups 0..3, lvl2 rows -> lvl3 pair + lvl4 node
    if (gg < 4) {
        float4 k[4], v[4];
#pragma unroll
        for (int j = 0; j < 4; ++j) {
            k[j] = Kb[(4 * gg + j) * ROWF4 + t];
            v[j] = Vb[(4 * gg + j) * ROWF4 + t];
        }
        int s3 = 1536 + c * 8 + 2 * gg;
        int s4 = 1792 + c * 4 + gg;
        float4 kg, vg;
        quad_step(k, v, Kw4, Vw4, wsBase + (size_t)s3 * HSTRIDE,
                  wsBase + (size_t)s4 * HSTRIDE, t, kg, vg);
        Kb[(16 + gg) * ROWF4 + t] = kg;  Vb[(16 + gg) * ROWF4 + t] = vg;
    }
    __syncthreads();
    // Round C: group 0, lvl4 rows -> lvl5 pair + lvl6 node
    if (gg == 0) {
        float4 k[4], v[4];
#pragma unroll
        for (int j = 0; j < 4; ++j) {
            k[j] = Kb[(16 + j) * ROWF4 + t];
            v[j] = Vb[(16 + j) * ROWF4 + t];
        }
        int s5 = 1920 + c * 2;
        int s6 = 1984 + c;
        float4 kg, vg;
        quad_step(k, v, Kw4, Vw4, wsBase + (size_t)s5 * HSTRIDE,
                  wsBase + (size_t)s6 * HSTRIDE, t, kg, vg);
    }
}

// ---- Kernel B: tree levels 7..10 for one (b,h). 32 blocks, 2 rounds, 1 barrier.
__global__ __launch_bounds__(256) void tree_top(float* __restrict__ Kw,
                                                float* __restrict__ Vw) {
    __shared__ float4 Kb[8 * ROWF4];    // lvl8 nodes
    __shared__ float4 Vb[8 * ROWF4];
    float4* Kw4 = (float4*)Kw;
    float4* Vw4 = (float4*)Vw;

    int h = blockIdx.x & 15, b = blockIdx.x >> 4;
    int lane = threadIdx.x & 63;
    int gg = (threadIdx.x >> 6) * 4 + (lane >> 4);
    int t = lane & 15;
    size_t wsBase = (size_t)(b * WSSLOTS) * HSTRIDE + h * ROWF4;

    // Round A: groups 0..7: 4 lvl6 rows -> lvl7 pair + lvl8 node
    if (gg < 8) {
        float4 k[4], v[4];
#pragma unroll
        for (int j = 0; j < 4; ++j) {
            size_t r = wsBase + (size_t)(1984 + 4 * gg + j) * HSTRIDE + t;
            k[j] = Kw4[r]; v[j] = Vw4[r];
        }
        int s7 = 2016 + 2 * gg;
        int s8 = 2032 + gg;
        float4 kg, vg;
        quad_step(k, v, Kw4, Vw4, wsBase + (size_t)s7 * HSTRIDE,
                  wsBase + (size_t)s8 * HSTRIDE, t, kg, vg);
        Kb[gg * ROWF4 + t] = kg;  Vb[gg * ROWF4 + t] = vg;
    }
    __syncthreads();
    // Round B: groups 0..1: 4 lvl8 rows -> lvl9 pair + lvl10 node
    if (gg < 2) {
        float4 k[4], v[4];
#pragma unroll
        for (int j = 0; j < 4; ++j) {
            k[j] = Kb[(4 * gg + j) * ROWF4 + t];
            v[j] = Vb[(4 * gg + j) * ROWF4 + t];
        }
        int s9  = 2040 + 2 * gg;
        int s10 = 2044 + gg;
        float4 kg, vg;
        quad_step(k, v, Kw4, Vw4, wsBase + (size_t)s9 * HSTRIDE,
                  wsBase + (size_t)s10 * HSTRIDE, t, kg, vg);
    }
}

// ---- Kernel C: attention. One wave = 4 heads of one (b,n). 4096 blocks.
// Masked columns have weight exactly 0 -> skip their K/V loads, dots, and
// V-accumulation entirely (mask is wave-uniform: same n across the wave).
// q is pre-scaled by SCALE (4 muls instead of 12 post-reduction muls).
__global__ __launch_bounds__(256) void attn(const float* __restrict__ Q,
                                            const float* __restrict__ K,
                                            const float* __restrict__ V,
                                            const float* __restrict__ Kw,
                                            const float* __restrict__ Vw,
                                            float* __restrict__ out) {
    const float4* Q4 = (const float4*)Q;
    const float4* K4 = (const float4*)K;
    const float4* V4 = (const float4*)V;
    const float4* Kw4 = (const float4*)Kw;
    const float4* Vw4 = (const float4*)Vw;
    float4* O4 = (float4*)out;

    int bid = blockIdx.x;                              // 0..4095
    int vbid = ((bid & 7) << 9) | (bid >> 3);          // bijective XCD remap
    int w = vbid * 4 + (threadIdx.x >> 6);             // wave id over B*N*(H/4)
    int lane = threadIdx.x & 63;
    int g = lane >> 4;
    int t = lane & 15;
    int h = (w & 3) * 4 + g;
    int n = (w >> 2) & (NSEQ - 1);
    int b = w >> 13;

    int row0 = (b * NSEQ + n) * HSTRIDE;               // self leaf / Q / out
    int row1 = (b * NSEQ + (n ^ 1)) * HSTRIDE;         // sibling leaf
    int rowt[10];
#pragma unroll
    for (int l = 2; l < 12; ++l) {
        int j = l - 1;
        int slot = level_offset(j) - NSEQ + ((n >> j) ^ 1);
        rowt[l - 2] = (b * WSSLOTS + slot) * HSTRIDE;
    }
    int hoff = h * ROWF4 + t;

    // column l active iff l==0 or bit (l-1) of n set (wave-uniform)
    unsigned active = 1u | (((unsigned)n & 0x7FFu) << 1);

    float4 q4 = Q4[row0 + hoff];
    q4.x *= SCALE; q4.y *= SCALE; q4.z *= SCALE; q4.w *= SCALE;

    float4 k[12], v[12];
    float s[12];
    k[0] = K4[row0 + hoff];
    v[0] = V4[row0 + hoff];
    if (active & 2u) { k[1] = K4[row1 + hoff]; v[1] = V4[row1 + hoff]; }
#pragma unroll
    for (int l = 2; l < 12; ++l) {
        if (active & (1u << l)) {
            k[l] = Kw4[rowt[l - 2] + hoff];
            v[l] = Vw4[rowt[l - 2] + hoff];
        }
    }
    s[0] = dot4(q4, k[0]);
#pragma unroll
    for (int l = 1; l < 12; ++l)
        s[l] = (active & (1u << l)) ? dot4(q4, k[l]) : 0.f;

#pragma unroll
    for (int m = 1; m < 16; m <<= 1) {
#pragma unroll
        for (int l = 0; l < 12; ++l) s[l] += __shfl_xor(s[l], m, 64);
    }

    float mx = -3.402823466e+38f;
#pragma unroll
    for (int l = 0; l < 12; ++l)
        if (active & (1u << l)) mx = fmaxf(mx, s[l]);
    float sum = 0.f;
#pragma unroll
    for (int l = 0; l < 12; ++l) {
        float e = (active & (1u << l)) ? __expf(s[l] - mx) : 0.f;
        s[l] = e;
        sum += e;
    }
    float inv = 1.0f / sum;

    float4 o = make_float4(0.f, 0.f, 0.f, 0.f);
    o.x += s[0] * v[0].x; o.y += s[0] * v[0].y;
    o.z += s[0] * v[0].z; o.w += s[0] * v[0].w;
#pragma unroll
    for (int l = 1; l < 12; ++l) {
        if (active & (1u << l)) {
            o.x += s[l] * v[l].x; o.y += s[l] * v[l].y;
            o.z += s[l] * v[l].z; o.w += s[l] * v[l].w;
        }
    }
    O4[row0 + hoff] = make_float4(o.x * inv, o.y * inv, o.z * inv, o.w * inv);
}

extern "C" void kernel_launch(void* const* d_in, const int* in_sizes, int n_in,
                              void* d_out, int out_size, void* d_ws, size_t ws_size,
                              hipStream_t stream) {
    const float* Q = (const float*)d_in[0];
    const float* K = (const float*)d_in[1];
    const float* V = (const float*)d_in[2];
    float* out = (float*)d_out;
    float* Kw = (float*)d_ws;              // 16.78 MiB
    float* Vw = Kw + WSELEMS;              // 16.78 MiB

    tree_low<<<1024, 256, 0, stream>>>(K, V, Kw, Vw);
    tree_top<<<BATCH * HEADS, 256, 0, stream>>>(Kw, Vw);
    attn<<<(BATCH * NSEQ * (HEADS / 4)) / 4, 256, 0, stream>>>(Q, K, V, Kw, Vw, out);
}

// Round 10
// 115.274 us; speedup vs baseline: 2.0421x; 1.0208x over previous
//
#include <hip/hip_runtime.h>

#define NSEQ   2048
#define HEADS  16
#define DIM    64
#define BATCH  2
#define SCALE  0.125f      // 1/sqrt(64)

// Workspace layout (bf16 tree nodes):
//   Kw  : bf16 [b][slot][h][d]   8.39 MB   (slot = g - NSEQ, g in [NSEQ, 2N-2))
//   Vw  : bf16 [b][slot][h][d]   8.39 MB
//   Kw6 : fp32 [b][32][h][d]     262 KB    (lvl6 stash so tree_top builds from fp32)
//   Vw6 : fp32 [b][32][h][d]     262 KB
// Slot map: lvl1 0..1023, lvl2 1024.., lvl3 1536.., lvl4 1792.., lvl5 1920..,
// lvl6 1984.., lvl7 2016.., lvl8 2032.., lvl9 2040.., lvl10 2044,2045.
// All tree math is fp32; bf16 is a single final rounding per stored node
// (LDS and the lvl6 stash carry fp32 between levels - no error compounding).
// NOTE (R8 lesson): do NOT fuse tree_top via last-block + __threadfence();
// per-block device-scope fences cost ~100 µs at 1024 blocks on MI355X.
// The kernel-launch boundary is the cheap cross-XCD coherence point.
#define WSSLOTS 2048
#define WSELEMS ((size_t)BATCH * WSSLOTS * HEADS * DIM)   // bf16 elements per array
#define ROWF4   (DIM / 4)              // 16 granules per row (float4 or ushort4)
#define HSTRIDE (HEADS * ROWF4)        // granule stride between rows (n or slot)

__device__ __forceinline__ int level_offset(int j) {
    return (j == 0) ? 0 : (2 * NSEQ - ((2 * NSEQ) >> j));
}

__device__ __forceinline__ float dot4(float4 a, float4 b) {
    return a.x * b.x + a.y * b.y + a.z * b.z + a.w * b.w;
}

// ---- bf16 pack/unpack (RNE) ----
__device__ __forceinline__ unsigned short bf16rne(float x) {
    unsigned u = __float_as_uint(x);
    return (unsigned short)((u + 0x7FFFu + ((u >> 16) & 1u)) >> 16);
}
__device__ __forceinline__ ushort4 packbf4(float4 a) {
    ushort4 r;
    r.x = bf16rne(a.x); r.y = bf16rne(a.y);
    r.z = bf16rne(a.z); r.w = bf16rne(a.w);
    return r;
}
__device__ __forceinline__ float4 unpackbf4(ushort4 a) {
    return make_float4(__uint_as_float((unsigned)a.x << 16),
                       __uint_as_float((unsigned)a.y << 16),
                       __uint_as_float((unsigned)a.z << 16),
                       __uint_as_float((unsigned)a.w << 16));
}

__device__ __forceinline__ void reduce3_16(float& a, float& b, float& c) {
#pragma unroll
    for (int m = 1; m < 16; m <<= 1) {
        a += __shfl_xor(a, m, 64);
        b += __shfl_xor(b, m, 64);
        c += __shfl_xor(c, m, 64);
    }
}

__device__ __forceinline__ void reduce6_16(float& a, float& b, float& c,
                                           float& d, float& e, float& f) {
#pragma unroll
    for (int m = 1; m < 16; m <<= 1) {
        a += __shfl_xor(a, m, 64);
        b += __shfl_xor(b, m, 64);
        c += __shfl_xor(c, m, 64);
        d += __shfl_xor(d, m, 64);
        e += __shfl_xor(e, m, 64);
        f += __shfl_xor(f, m, 64);
    }
}

// Parent = 3-way softmax mix of {mean, child0, child1}; 16 lanes / parent.
__device__ __forceinline__ void make_parent4(float4 k0, float4 k1, float4 v0, float4 v1,
                                             float4& kc, float4& vc) {
    float4 kp, vp;
    kp.x = 0.5f * (k0.x + k1.x); kp.y = 0.5f * (k0.y + k1.y);
    kp.z = 0.5f * (k0.z + k1.z); kp.w = 0.5f * (k0.w + k1.w);
    vp.x = 0.5f * (v0.x + v1.x); vp.y = 0.5f * (v0.y + v1.y);
    vp.z = 0.5f * (v0.z + v1.z); vp.w = 0.5f * (v0.w + v1.w);
    float ss = dot4(kp, kp), sa = dot4(kp, k0), sb = dot4(kp, k1);
    reduce3_16(ss, sa, sb);
    ss *= SCALE; sa *= SCALE; sb *= SCALE;
    float mx = fmaxf(ss, fmaxf(sa, sb));
    float es = __expf(ss - mx), ea = __expf(sa - mx), eb = __expf(sb - mx);
    float inv = 1.0f / (es + ea + eb + 1e-9f);
    es *= inv; ea *= inv; eb *= inv;
    kc.x = es * kp.x + ea * k0.x + eb * k1.x;
    kc.y = es * kp.y + ea * k0.y + eb * k1.y;
    kc.z = es * kp.z + ea * k0.z + eb * k1.z;
    kc.w = es * kp.w + ea * k0.w + eb * k1.w;
    vc.x = es * vp.x + ea * v0.x + eb * v1.x;
    vc.y = es * vp.y + ea * v0.y + eb * v1.y;
    vc.z = es * vp.z + ea * v0.z + eb * v1.z;
    vc.w = es * vp.w + ea * v0.w + eb * v1.w;
}

// Two independent sibling mixes with an interleaved 6-value butterfly (ILP).
__device__ __forceinline__ void make_parent_pair4(const float4* k, const float4* v,
                                                  float4& ka, float4& va,
                                                  float4& kb, float4& vb) {
    float4 kpa, vpa, kpb, vpb;
    kpa.x = 0.5f * (k[0].x + k[1].x); kpa.y = 0.5f * (k[0].y + k[1].y);
    kpa.z = 0.5f * (k[0].z + k[1].z); kpa.w = 0.5f * (k[0].w + k[1].w);
    vpa.x = 0.5f * (v[0].x + v[1].x); vpa.y = 0.5f * (v[0].y + v[1].y);
    vpa.z = 0.5f * (v[0].z + v[1].z); vpa.w = 0.5f * (v[0].w + v[1].w);
    kpb.x = 0.5f * (k[2].x + k[3].x); kpb.y = 0.5f * (k[2].y + k[3].y);
    kpb.z = 0.5f * (k[2].z + k[3].z); kpb.w = 0.5f * (k[2].w + k[3].w);
    vpb.x = 0.5f * (v[2].x + v[3].x); vpb.y = 0.5f * (v[2].y + v[3].y);
    vpb.z = 0.5f * (v[2].z + v[3].z); vpb.w = 0.5f * (v[2].w + v[3].w);
    float ssa = dot4(kpa, kpa), saa = dot4(kpa, k[0]), sba = dot4(kpa, k[1]);
    float ssb = dot4(kpb, kpb), sab = dot4(kpb, k[2]), sbb = dot4(kpb, k[3]);
    reduce6_16(ssa, saa, sba, ssb, sab, sbb);
    ssa *= SCALE; saa *= SCALE; sba *= SCALE;
    ssb *= SCALE; sab *= SCALE; sbb *= SCALE;
    float mxa = fmaxf(ssa, fmaxf(saa, sba));
    float mxb = fmaxf(ssb, fmaxf(sab, sbb));
    float esa = __expf(ssa - mxa), eaa = __expf(saa - mxa), eba = __expf(sba - mxa);
    float esb = __expf(ssb - mxb), eab = __expf(sab - mxb), ebb = __expf(sbb - mxb);
    float iva = 1.0f / (esa + eaa + eba + 1e-9f);
    float ivb = 1.0f / (esb + eab + ebb + 1e-9f);
    esa *= iva; eaa *= iva; eba *= iva;
    esb *= ivb; eab *= ivb; ebb *= ivb;
    ka.x = esa * kpa.x + eaa * k[0].x + eba * k[1].x;
    ka.y = esa * kpa.y + eaa * k[0].y + eba * k[1].y;
    ka.z = esa * kpa.z + eaa * k[0].z + eba * k[1].z;
    ka.w = esa * kpa.w + eaa * k[0].w + eba * k[1].w;
    va.x = esa * vpa.x + eaa * v[0].x + eba * v[1].x;
    va.y = esa * vpa.y + eaa * v[0].y + eba * v[1].y;
    va.z = esa * vpa.z + eaa * v[0].z + eba * v[1].z;
    va.w = esa * vpa.w + eaa * v[0].w + eba * v[1].w;
    kb.x = esb * kpb.x + eab * k[2].x + ebb * k[3].x;
    kb.y = esb * kpb.y + eab * k[2].y + ebb * k[3].y;
    kb.z = esb * kpb.z + eab * k[2].z + ebb * k[3].z;
    kb.w = esb * kpb.w + eab * k[2].w + ebb * k[3].w;
    vb.x = esb * vpb.x + eab * v[2].x + ebb * v[3].x;
    vb.y = esb * vpb.y + eab * v[2].y + ebb * v[3].y;
    vb.z = esb * vpb.z + eab * v[2].z + ebb * v[3].z;
    vb.w = esb * vpb.w + eab * v[2].w + ebb * v[3].w;
}

// 4-ary consolidation: 4 child rows -> 2 parents (stored bf16) + 1 grandparent
// (stored bf16, returned fp32).
__device__ __forceinline__ void quad_step(const float4* k, const float4* v,
                                          ushort4* Kw4, ushort4* Vw4,
                                          size_t pRow0, size_t gRow,   // granule offsets (+t)
                                          int t,
                                          float4& kg, float4& vg) {
    float4 ka, va, kb, vb;
    make_parent_pair4(k, v, ka, va, kb, vb);
    Kw4[pRow0 + t] = packbf4(ka);            Vw4[pRow0 + t] = packbf4(va);
    Kw4[pRow0 + HSTRIDE + t] = packbf4(kb);  Vw4[pRow0 + HSTRIDE + t] = packbf4(vb);
    make_parent4(ka, kb, va, vb, kg, vg);
    Kw4[gRow + t] = packbf4(kg);             Vw4[gRow + t] = packbf4(vg);
}

// ---- Kernel A: tree levels 1..6 for one 64-leaf chunk. 1024 blocks (b,h,c).
__global__ __launch_bounds__(256) void tree_low(const float* __restrict__ K,
                                                const float* __restrict__ V,
                                                unsigned short* __restrict__ Kw,
                                                unsigned short* __restrict__ Vw,
                                                float* __restrict__ Kw6,
                                                float* __restrict__ Vw6) {
    __shared__ float4 Kb[20 * ROWF4];   // rows [0,16): lvl2 ; rows [16,20): lvl4
    __shared__ float4 Vb[20 * ROWF4];
    const float4* K4 = (const float4*)K;
    const float4* V4 = (const float4*)V;
    ushort4* Kw4 = (ushort4*)Kw;
    ushort4* Vw4 = (ushort4*)Vw;
    float4* Kw6f = (float4*)Kw6;
    float4* Vw6f = (float4*)Vw6;

    int bid = blockIdx.x;
    int c = bid & 31;
    int h = (bid >> 5) & 15;
    int b = bid >> 9;
    int lane = threadIdx.x & 63;
    int gg = (threadIdx.x >> 6) * 4 + (lane >> 4);   // group 0..15
    int t = lane & 15;

    size_t wsBase = (size_t)(b * WSSLOTS) * HSTRIDE + h * ROWF4;  // + slot*HSTRIDE + t

    // Round A: 16 groups, 4 leaves each -> lvl1 pair + lvl2 node
    {
        int n0 = c * 64 + 4 * gg;
        const float4* Kr = K4 + ((size_t)((b * NSEQ + n0) * HEADS + h)) * ROWF4;
        const float4* Vr = V4 + ((size_t)((b * NSEQ + n0) * HEADS + h)) * ROWF4;
        float4 k[4], v[4];
#pragma unroll
        for (int j = 0; j < 4; ++j) { k[j] = Kr[j * HSTRIDE + t]; v[j] = Vr[j * HSTRIDE + t]; }
        int s1 = c * 32 + 2 * gg;          // lvl1 slots s1, s1+1
        int s2 = 1024 + c * 16 + gg;       // lvl2 slot
        float4 kg, vg;
        quad_step(k, v, Kw4, Vw4, wsBase + (size_t)s1 * HSTRIDE,
                  wsBase + (size_t)s2 * HSTRIDE, t, kg, vg);
        Kb[gg * ROWF4 + t] = kg;  Vb[gg * ROWF4 + t] = vg;
    }
    __syncthreads();
    // Round B: groups 0..3, lvl2 rows -> lvl3 pair + lvl4 node
    if (gg < 4) {
        float4 k[4], v[4];
#pragma unroll
        for (int j = 0; j < 4; ++j) {
            k[j] = Kb[(4 * gg + j) * ROWF4 + t];
            v[j] = Vb[(4 * gg + j) * ROWF4 + t];
        }
        int s3 = 1536 + c * 8 + 2 * gg;
        int s4 = 1792 + c * 4 + gg;
        float4 kg, vg;
        quad_step(k, v, Kw4, Vw4, wsBase + (size_t)s3 * HSTRIDE,
                  wsBase + (size_t)s4 * HSTRIDE, t, kg, vg);
        Kb[(16 + gg) * ROWF4 + t] = kg;  Vb[(16 + gg) * ROWF4 + t] = vg;
    }
    __syncthreads();
    // Round C: group 0, lvl4 rows -> lvl5 pair + lvl6 node (+ fp32 lvl6 stash)
    if (gg == 0) {
        float4 k[4], v[4];
#pragma unroll
        for (int j = 0; j < 4; ++j) {
            k[j] = Kb[(16 + j) * ROWF4 + t];
            v[j] = Vb[(16 + j) * ROWF4 + t];
        }
        int s5 = 1920 + c * 2;
        int s6 = 1984 + c;
        float4 kg, vg;
        quad_step(k, v, Kw4, Vw4, wsBase + (size_t)s5 * HSTRIDE,
                  wsBase + (size_t)s6 * HSTRIDE, t, kg, vg);
        size_t st = ((size_t)((b * 32 + c) * HEADS + h)) * ROWF4 + t;
        Kw6f[st] = kg;  Vw6f[st] = vg;     // fp32 stash for tree_top
    }
}

// ---- Kernel B: tree levels 7..10 for one (b,h). 32 blocks, 2 rounds, 1 barrier.
// Builds from the fp32 lvl6 stash (no bf16 re-rounding compounding).
__global__ __launch_bounds__(256) void tree_top(unsigned short* __restrict__ Kw,
                                                unsigned short* __restrict__ Vw,
                                                const float* __restrict__ Kw6,
                                                const float* __restrict__ Vw6) {
    __shared__ float4 Kb[8 * ROWF4];    // lvl8 nodes (fp32)
    __shared__ float4 Vb[8 * ROWF4];
    ushort4* Kw4 = (ushort4*)Kw;
    ushort4* Vw4 = (ushort4*)Vw;
    const float4* Kw6f = (const float4*)Kw6;
    const float4* Vw6f = (const float4*)Vw6;

    int h = blockIdx.x & 15, b = blockIdx.x >> 4;
    int lane = threadIdx.x & 63;
    int gg = (threadIdx.x >> 6) * 4 + (lane >> 4);
    int t = lane & 15;
    size_t wsBase = (size_t)(b * WSSLOTS) * HSTRIDE + h * ROWF4;

    // Round A: groups 0..7: 4 fp32 lvl6 rows -> lvl7 pair + lvl8 node
    if (gg < 8) {
        float4 k[4], v[4];
#pragma unroll
        for (int j = 0; j < 4; ++j) {
            size_t r = ((size_t)((b * 32 + 4 * gg + j) * HEADS + h)) * ROWF4 + t;
            k[j] = Kw6f[r]; v[j] = Vw6f[r];
        }
        int s7 = 2016 + 2 * gg;
        int s8 = 2032 + gg;
        float4 kg, vg;
        quad_step(k, v, Kw4, Vw4, wsBase + (size_t)s7 * HSTRIDE,
                  wsBase + (size_t)s8 * HSTRIDE, t, kg, vg);
        Kb[gg * ROWF4 + t] = kg;  Vb[gg * ROWF4 + t] = vg;
    }
    __syncthreads();
    // Round B: groups 0..1: 4 fp32 lvl8 rows -> lvl9 pair + lvl10 node
    if (gg < 2) {
        float4 k[4], v[4];
#pragma unroll
        for (int j = 0; j < 4; ++j) {
            k[j] = Kb[(4 * gg + j) * ROWF4 + t];
            v[j] = Vb[(4 * gg + j) * ROWF4 + t];
        }
        int s9  = 2040 + 2 * gg;
        int s10 = 2044 + gg;
        float4 kg, vg;
        quad_step(k, v, Kw4, Vw4, wsBase + (size_t)s9 * HSTRIDE,
                  wsBase + (size_t)s10 * HSTRIDE, t, kg, vg);
    }
}

// ---- Kernel C: attention. One wave = 4 heads of one (b,n). 4096 blocks.
// Tree-node gathers are bf16 (half fetch bytes, half register footprint);
// leaves (cols 0,1) stay fp32. Masked columns skipped (wave-uniform).
__global__ __launch_bounds__(256) void attn(const float* __restrict__ Q,
                                            const float* __restrict__ K,
                                            const float* __restrict__ V,
                                            const unsigned short* __restrict__ Kw,
                                            const unsigned short* __restrict__ Vw,
                                            float* __restrict__ out) {
    const float4* Q4 = (const float4*)Q;
    const float4* K4 = (const float4*)K;
    const float4* V4 = (const float4*)V;
    const ushort4* Kw4 = (const ushort4*)Kw;
    const ushort4* Vw4 = (const ushort4*)Vw;
    float4* O4 = (float4*)out;

    int bid = blockIdx.x;                              // 0..4095
    int vbid = ((bid & 7) << 9) | (bid >> 3);          // bijective XCD remap
    int w = vbid * 4 + (threadIdx.x >> 6);             // wave id over B*N*(H/4)
    int lane = threadIdx.x & 63;
    int g = lane >> 4;
    int t = lane & 15;
    int h = (w & 3) * 4 + g;
    int n = (w >> 2) & (NSEQ - 1);
    int b = w >> 13;

    int row0 = (b * NSEQ + n) * HSTRIDE;               // self leaf / Q / out
    int row1 = (b * NSEQ + (n ^ 1)) * HSTRIDE;         // sibling leaf
    int rowt[10];
#pragma unroll
    for (int l = 2; l < 12; ++l) {
        int j = l - 1;
        int slot = level_offset(j) - NSEQ + ((n >> j) ^ 1);
        rowt[l - 2] = (b * WSSLOTS + slot) * HSTRIDE;
    }
    int hoff = h * ROWF4 + t;

    // column l active iff l==0 or bit (l-1) of n set (wave-uniform)
    unsigned active = 1u | (((unsigned)n & 0x7FFu) << 1);

    float4 q4 = Q4[row0 + hoff];
    q4.x *= SCALE; q4.y *= SCALE; q4.z *= SCALE; q4.w *= SCALE;

    float4 k0 = K4[row0 + hoff];
    float4 v0 = V4[row0 + hoff];
    float4 k1, v1;
    if (active & 2u) { k1 = K4[row1 + hoff]; v1 = V4[row1 + hoff]; }
    ushort4 kb[10], vb[10];
#pragma unroll
    for (int l = 2; l < 12; ++l) {
        if (active & (1u << l)) {
            kb[l - 2] = Kw4[rowt[l - 2] + hoff];
            vb[l - 2] = Vw4[rowt[l - 2] + hoff];
        }
    }

    float s[12];
    s[0] = dot4(q4, k0);
    s[1] = (active & 2u) ? dot4(q4, k1) : 0.f;
#pragma unroll
    for (int l = 2; l < 12; ++l)
        s[l] = (active & (1u << l)) ? dot4(q4, unpackbf4(kb[l - 2])) : 0.f;

#pragma unroll
    for (int m = 1; m < 16; m <<= 1) {
#pragma unroll
        for (int l = 0; l < 12; ++l) s[l] += __shfl_xor(s[l], m, 64);
    }

    float mx = -3.402823466e+38f;
#pragma unroll
    for (int l = 0; l < 12; ++l)
        if (active & (1u << l)) mx = fmaxf(mx, s[l]);
    float sum = 0.f;
#pragma unroll
    for (int l = 0; l < 12; ++l) {
        float e = (active & (1u << l)) ? __expf(s[l] - mx) : 0.f;
        s[l] = e;
        sum += e;
    }
    float inv = 1.0f / sum;

    float4 o = make_float4(0.f, 0.f, 0.f, 0.f);
    o.x += s[0] * v0.x; o.y += s[0] * v0.y;
    o.z += s[0] * v0.z; o.w += s[0] * v0.w;
    if (active & 2u) {
        o.x += s[1] * v1.x; o.y += s[1] * v1.y;
        o.z += s[1] * v1.z; o.w += s[1] * v1.w;
    }
#pragma unroll
    for (int l = 2; l < 12; ++l) {
        if (active & (1u << l)) {
            float4 vv = unpackbf4(vb[l - 2]);
            o.x += s[l] * vv.x; o.y += s[l] * vv.y;
            o.z += s[l] * vv.z; o.w += s[l] * vv.w;
        }
    }
    O4[row0 + hoff] = make_float4(o.x * inv, o.y * inv, o.z * inv, o.w * inv);
}

extern "C" void kernel_launch(void* const* d_in, const int* in_sizes, int n_in,
                              void* d_out, int out_size, void* d_ws, size_t ws_size,
                              hipStream_t stream) {
    const float* Q = (const float*)d_in[0];
    const float* K = (const float*)d_in[1];
    const float* V = (const float*)d_in[2];
    float* out = (float*)d_out;
    unsigned short* Kw = (unsigned short*)d_ws;        // bf16, 8.39 MB
    unsigned short* Vw = Kw + WSELEMS;                 // bf16, 8.39 MB
    float* Kw6 = (float*)(Vw + WSELEMS);               // fp32 lvl6 stash, 262 KB
    float* Vw6 = Kw6 + (size_t)BATCH * 32 * HEADS * DIM;

    tree_low<<<1024, 256, 0, stream>>>(K, V, Kw, Vw, Kw6, Vw6);
    tree_top<<<BATCH * HEADS, 256, 0, stream>>>(Kw, Vw, Kw6, Vw6);
    attn<<<(BATCH * NSEQ * (HEADS / 4)) / 4, 256, 0, stream>>>(Q, K, V, Kw, Vw, out);
}

// Round 11
// 114.731 us; speedup vs baseline: 2.0518x; 1.0047x over previous
//
#include <hip/hip_runtime.h>

#define NSEQ   2048
#define HEADS  16
#define DIM    64
#define BATCH  2
#define SCALE  0.125f      // 1/sqrt(64)

// Workspace layout:
//   KVw : bf16 combined rows [b][slot][h][granule t]  where granule t (16 B)
//         = {k[4t..4t+3], v[4t..4t+3]} both bf16x4.  16.78 MB total.
//         One dwordx4 per (slot,h,t) fetches BOTH K and V fragments -> halves
//         the scattered-load count in attn (gather-latency-bound, R10).
//   Kw6/Vw6 : fp32 lvl6 stash [b][32][h][d], 262 KB each (tree_top builds
//         from fp32 so bf16 rounding never compounds).
// Slot map: lvl1 0..1023, lvl2 1024.., lvl3 1536.., lvl4 1792.., lvl5 1920..,
// lvl6 1984.., lvl7 2016.., lvl8 2032.., lvl9 2040.., lvl10 2044,2045.
// Invariant: parent(level_offset(j)+i) = level_offset(j+1)+i/2.
// NOTE (R8 lesson): do NOT fuse tree_top via last-block + __threadfence();
// per-block device-scope fences cost ~100 µs at 1024 blocks on MI355X.
// The kernel-launch boundary is the cheap cross-XCD coherence point.
#define WSSLOTS 2048
#define ROWF4   (DIM / 4)              // 16 granules per row
#define HSTRIDE (HEADS * ROWF4)        // granule stride between rows (n or slot)
#define KVBYTES ((size_t)BATCH * WSSLOTS * HEADS * 256)   // combined ws bytes

__device__ __forceinline__ int level_offset(int j) {
    return (j == 0) ? 0 : (2 * NSEQ - ((2 * NSEQ) >> j));
}

__device__ __forceinline__ float dot4(float4 a, float4 b) {
    return a.x * b.x + a.y * b.y + a.z * b.z + a.w * b.w;
}

// ---- bf16 pack/unpack (RNE) ----
__device__ __forceinline__ unsigned short bf16rne(float x) {
    unsigned u = __float_as_uint(x);
    return (unsigned short)((u + 0x7FFFu + ((u >> 16) & 1u)) >> 16);
}
__device__ __forceinline__ unsigned pack2(float a, float b) {
    return (unsigned)bf16rne(a) | ((unsigned)bf16rne(b) << 16);
}
__device__ __forceinline__ uint4 packKV(float4 k, float4 v) {
    return make_uint4(pack2(k.x, k.y), pack2(k.z, k.w),
                      pack2(v.x, v.y), pack2(v.z, v.w));
}
__device__ __forceinline__ float2 unpack2(unsigned u) {
    return make_float2(__uint_as_float(u << 16),
                       __uint_as_float(u & 0xFFFF0000u));
}
__device__ __forceinline__ float4 unpackK(uint4 p) {
    float2 a = unpack2(p.x), b = unpack2(p.y);
    return make_float4(a.x, a.y, b.x, b.y);
}
__device__ __forceinline__ float4 unpackV(uint4 p) {
    float2 a = unpack2(p.z), b = unpack2(p.w);
    return make_float4(a.x, a.y, b.x, b.y);
}

__device__ __forceinline__ void reduce3_16(float& a, float& b, float& c) {
#pragma unroll
    for (int m = 1; m < 16; m <<= 1) {
        a += __shfl_xor(a, m, 64);
        b += __shfl_xor(b, m, 64);
        c += __shfl_xor(c, m, 64);
    }
}

__device__ __forceinline__ void reduce6_16(float& a, float& b, float& c,
                                           float& d, float& e, float& f) {
#pragma unroll
    for (int m = 1; m < 16; m <<= 1) {
        a += __shfl_xor(a, m, 64);
        b += __shfl_xor(b, m, 64);
        c += __shfl_xor(c, m, 64);
        d += __shfl_xor(d, m, 64);
        e += __shfl_xor(e, m, 64);
        f += __shfl_xor(f, m, 64);
    }
}

// Parent = 3-way softmax mix of {mean, child0, child1}; 16 lanes / parent.
__device__ __forceinline__ void make_parent4(float4 k0, float4 k1, float4 v0, float4 v1,
                                             float4& kc, float4& vc) {
    float4 kp, vp;
    kp.x = 0.5f * (k0.x + k1.x); kp.y = 0.5f * (k0.y + k1.y);
    kp.z = 0.5f * (k0.z + k1.z); kp.w = 0.5f * (k0.w + k1.w);
    vp.x = 0.5f * (v0.x + v1.x); vp.y = 0.5f * (v0.y + v1.y);
    vp.z = 0.5f * (v0.z + v1.z); vp.w = 0.5f * (v0.w + v1.w);
    float ss = dot4(kp, kp), sa = dot4(kp, k0), sb = dot4(kp, k1);
    reduce3_16(ss, sa, sb);
    ss *= SCALE; sa *= SCALE; sb *= SCALE;
    float mx = fmaxf(ss, fmaxf(sa, sb));
    float es = __expf(ss - mx), ea = __expf(sa - mx), eb = __expf(sb - mx);
    float inv = 1.0f / (es + ea + eb + 1e-9f);
    es *= inv; ea *= inv; eb *= inv;
    kc.x = es * kp.x + ea * k0.x + eb * k1.x;
    kc.y = es * kp.y + ea * k0.y + eb * k1.y;
    kc.z = es * kp.z + ea * k0.z + eb * k1.z;
    kc.w = es * kp.w + ea * k0.w + eb * k1.w;
    vc.x = es * vp.x + ea * v0.x + eb * v1.x;
    vc.y = es * vp.y + ea * v0.y + eb * v1.y;
    vc.z = es * vp.z + ea * v0.z + eb * v1.z;
    vc.w = es * vp.w + ea * v0.w + eb * v1.w;
}

// Two independent sibling mixes with an interleaved 6-value butterfly (ILP).
__device__ __forceinline__ void make_parent_pair4(const float4* k, const float4* v,
                                                  float4& ka, float4& va,
                                                  float4& kb, float4& vb) {
    float4 kpa, vpa, kpb, vpb;
    kpa.x = 0.5f * (k[0].x + k[1].x); kpa.y = 0.5f * (k[0].y + k[1].y);
    kpa.z = 0.5f * (k[0].z + k[1].z); kpa.w = 0.5f * (k[0].w + k[1].w);
    vpa.x = 0.5f * (v[0].x + v[1].x); vpa.y = 0.5f * (v[0].y + v[1].y);
    vpa.z = 0.5f * (v[0].z + v[1].z); vpa.w = 0.5f * (v[0].w + v[1].w);
    kpb.x = 0.5f * (k[2].x + k[3].x); kpb.y = 0.5f * (k[2].y + k[3].y);
    kpb.z = 0.5f * (k[2].z + k[3].z); kpb.w = 0.5f * (k[2].w + k[3].w);
    vpb.x = 0.5f * (v[2].x + v[3].x); vpb.y = 0.5f * (v[2].y + v[3].y);
    vpb.z = 0.5f * (v[2].z + v[3].z); vpb.w = 0.5f * (v[2].w + v[3].w);
    float ssa = dot4(kpa, kpa), saa = dot4(kpa, k[0]), sba = dot4(kpa, k[1]);
    float ssb = dot4(kpb, kpb), sab = dot4(kpb, k[2]), sbb = dot4(kpb, k[3]);
    reduce6_16(ssa, saa, sba, ssb, sab, sbb);
    ssa *= SCALE; saa *= SCALE; sba *= SCALE;
    ssb *= SCALE; sab *= SCALE; sbb *= SCALE;
    float mxa = fmaxf(ssa, fmaxf(saa, sba));
    float mxb = fmaxf(ssb, fmaxf(sab, sbb));
    float esa = __expf(ssa - mxa), eaa = __expf(saa - mxa), eba = __expf(sba - mxa);
    float esb = __expf(ssb - mxb), eab = __expf(sab - mxb), ebb = __expf(sbb - mxb);
    float iva = 1.0f / (esa + eaa + eba + 1e-9f);
    float ivb = 1.0f / (esb + eab + ebb + 1e-9f);
    esa *= iva; eaa *= iva; eba *= iva;
    esb *= ivb; eab *= ivb; ebb *= ivb;
    ka.x = esa * kpa.x + eaa * k[0].x + eba * k[1].x;
    ka.y = esa * kpa.y + eaa * k[0].y + eba * k[1].y;
    ka.z = esa * kpa.z + eaa * k[0].z + eba * k[1].z;
    ka.w = esa * kpa.w + eaa * k[0].w + eba * k[1].w;
    va.x = esa * vpa.x + eaa * v[0].x + eba * v[1].x;
    va.y = esa * vpa.y + eaa * v[0].y + eba * v[1].y;
    va.z = esa * vpa.z + eaa * v[0].z + eba * v[1].z;
    va.w = esa * vpa.w + eaa * v[0].w + eba * v[1].w;
    kb.x = esb * kpb.x + eab * k[2].x + ebb * k[3].x;
    kb.y = esb * kpb.y + eab * k[2].y + ebb * k[3].y;
    kb.z = esb * kpb.z + eab * k[2].z + ebb * k[3].z;
    kb.w = esb * kpb.w + eab * k[2].w + ebb * k[3].w;
    vb.x = esb * vpb.x + eab * v[2].x + ebb * v[3].x;
    vb.y = esb * vpb.y + eab * v[2].y + ebb * v[3].y;
    vb.z = esb * vpb.z + eab * v[2].z + ebb * v[3].z;
    vb.w = esb * vpb.w + eab * v[2].w + ebb * v[3].w;
}

// 4-ary consolidation: 4 child rows -> 2 parents + 1 grandparent, each stored
// as ONE combined bf16 KV row (3 stores instead of 6).
__device__ __forceinline__ void quad_step(const float4* k, const float4* v,
                                          uint4* KVw,
                                          size_t pRow0, size_t gRow,   // granule offsets (+t)
                                          int t,
                                          float4& kg, float4& vg) {
    float4 ka, va, kb, vb;
    make_parent_pair4(k, v, ka, va, kb, vb);
    KVw[pRow0 + t] = packKV(ka, va);
    KVw[pRow0 + HSTRIDE + t] = packKV(kb, vb);
    make_parent4(ka, kb, va, vb, kg, vg);
    KVw[gRow + t] = packKV(kg, vg);
}

// ---- Kernel A: tree levels 1..6 for one 64-leaf chunk. 1024 blocks (b,h,c).
__global__ __launch_bounds__(256) void tree_low(const float* __restrict__ K,
                                                const float* __restrict__ V,
                                                uint4* __restrict__ KVw,
                                                float* __restrict__ Kw6,
                                                float* __restrict__ Vw6) {
    __shared__ float4 Kb[20 * ROWF4];   // rows [0,16): lvl2 ; rows [16,20): lvl4
    __shared__ float4 Vb[20 * ROWF4];
    const float4* K4 = (const float4*)K;
    const float4* V4 = (const float4*)V;
    float4* Kw6f = (float4*)Kw6;
    float4* Vw6f = (float4*)Vw6;

    int bid = blockIdx.x;
    int c = bid & 31;
    int h = (bid >> 5) & 15;
    int b = bid >> 9;
    int lane = threadIdx.x & 63;
    int gg = (threadIdx.x >> 6) * 4 + (lane >> 4);   // group 0..15
    int t = lane & 15;

    size_t wsBase = (size_t)(b * WSSLOTS) * HSTRIDE + h * ROWF4;  // + slot*HSTRIDE + t

    // Round A: 16 groups, 4 leaves each -> lvl1 pair + lvl2 node
    {
        int n0 = c * 64 + 4 * gg;
        const float4* Kr = K4 + ((size_t)((b * NSEQ + n0) * HEADS + h)) * ROWF4;
        const float4* Vr = V4 + ((size_t)((b * NSEQ + n0) * HEADS + h)) * ROWF4;
        float4 k[4], v[4];
#pragma unroll
        for (int j = 0; j < 4; ++j) { k[j] = Kr[j * HSTRIDE + t]; v[j] = Vr[j * HSTRIDE + t]; }
        int s1 = c * 32 + 2 * gg;          // lvl1 slots s1, s1+1
        int s2 = 1024 + c * 16 + gg;       // lvl2 slot
        float4 kg, vg;
        quad_step(k, v, KVw, wsBase + (size_t)s1 * HSTRIDE,
                  wsBase + (size_t)s2 * HSTRIDE, t, kg, vg);
        Kb[gg * ROWF4 + t] = kg;  Vb[gg * ROWF4 + t] = vg;
    }
    __syncthreads();
    // Round B: groups 0..3, lvl2 rows -> lvl3 pair + lvl4 node
    if (gg < 4) {
        float4 k[4], v[4];
#pragma unroll
        for (int j = 0; j < 4; ++j) {
            k[j] = Kb[(4 * gg + j) * ROWF4 + t];
            v[j] = Vb[(4 * gg + j) * ROWF4 + t];
        }
        int s3 = 1536 + c * 8 + 2 * gg;
        int s4 = 1792 + c * 4 + gg;
        float4 kg, vg;
        quad_step(k, v, KVw, wsBase + (size_t)s3 * HSTRIDE,
                  wsBase + (size_t)s4 * HSTRIDE, t, kg, vg);
        Kb[(16 + gg) * ROWF4 + t] = kg;  Vb[(16 + gg) * ROWF4 + t] = vg;
    }
    __syncthreads();
    // Round C: group 0, lvl4 rows -> lvl5 pair + lvl6 node (+ fp32 lvl6 stash)
    if (gg == 0) {
        float4 k[4], v[4];
#pragma unroll
        for (int j = 0; j < 4; ++j) {
            k[j] = Kb[(16 + j) * ROWF4 + t];
            v[j] = Vb[(16 + j) * ROWF4 + t];
        }
        int s5 = 1920 + c * 2;
        int s6 = 1984 + c;
        float4 kg, vg;
        quad_step(k, v, KVw, wsBase + (size_t)s5 * HSTRIDE,
                  wsBase + (size_t)s6 * HSTRIDE, t, kg, vg);
        size_t st = ((size_t)((b * 32 + c) * HEADS + h)) * ROWF4 + t;
        Kw6f[st] = kg;  Vw6f[st] = vg;     // fp32 stash for tree_top
    }
}

// ---- Kernel B: tree levels 7..10 for one (b,h). 32 blocks, 2 rounds, 1 barrier.
// Builds from the fp32 lvl6 stash (no bf16 re-rounding compounding).
__global__ __launch_bounds__(256) void tree_top(uint4* __restrict__ KVw,
                                                const float* __restrict__ Kw6,
                                                const float* __restrict__ Vw6) {
    __shared__ float4 Kb[8 * ROWF4];    // lvl8 nodes (fp32)
    __shared__ float4 Vb[8 * ROWF4];
    const float4* Kw6f = (const float4*)Kw6;
    const float4* Vw6f = (const float4*)Vw6;

    int h = blockIdx.x & 15, b = blockIdx.x >> 4;
    int lane = threadIdx.x & 63;
    int gg = (threadIdx.x >> 6) * 4 + (lane >> 4);
    int t = lane & 15;
    size_t wsBase = (size_t)(b * WSSLOTS) * HSTRIDE + h * ROWF4;

    // Round A: groups 0..7: 4 fp32 lvl6 rows -> lvl7 pair + lvl8 node
    if (gg < 8) {
        float4 k[4], v[4];
#pragma unroll
        for (int j = 0; j < 4; ++j) {
            size_t r = ((size_t)((b * 32 + 4 * gg + j) * HEADS + h)) * ROWF4 + t;
            k[j] = Kw6f[r]; v[j] = Vw6f[r];
        }
        int s7 = 2016 + 2 * gg;
        int s8 = 2032 + gg;
        float4 kg, vg;
        quad_step(k, v, KVw, wsBase + (size_t)s7 * HSTRIDE,
                  wsBase + (size_t)s8 * HSTRIDE, t, kg, vg);
        Kb[gg * ROWF4 + t] = kg;  Vb[gg * ROWF4 + t] = vg;
    }
    __syncthreads();
    // Round B: groups 0..1: 4 fp32 lvl8 rows -> lvl9 pair + lvl10 node
    if (gg < 2) {
        float4 k[4], v[4];
#pragma unroll
        for (int j = 0; j < 4; ++j) {
            k[j] = Kb[(4 * gg + j) * ROWF4 + t];
            v[j] = Vb[(4 * gg + j) * ROWF4 + t];
        }
        int s9  = 2040 + 2 * gg;
        int s10 = 2044 + gg;
        float4 kg, vg;
        quad_step(k, v, KVw, wsBase + (size_t)s9 * HSTRIDE,
                  wsBase + (size_t)s10 * HSTRIDE, t, kg, vg);
    }
}

// ---- Kernel C: attention. One wave = 4 heads of one (b,n). 4096 blocks.
// Tree-node gathers: ONE dwordx4 per active column fetches both K and V
// fragments (combined row) -> 10 scattered loads max instead of 20.
// Masked columns skipped entirely (wave-uniform mask).
__global__ __launch_bounds__(256) void attn(const float* __restrict__ Q,
                                            const float* __restrict__ K,
                                            const float* __restrict__ V,
                                            const uint4* __restrict__ KVw,
                                            float* __restrict__ out) {
    const float4* Q4 = (const float4*)Q;
    const float4* K4 = (const float4*)K;
    const float4* V4 = (const float4*)V;
    float4* O4 = (float4*)out;

    int bid = blockIdx.x;                              // 0..4095
    int vbid = ((bid & 7) << 9) | (bid >> 3);          // bijective XCD remap
    int w = vbid * 4 + (threadIdx.x >> 6);             // wave id over B*N*(H/4)
    int lane = threadIdx.x & 63;
    int g = lane >> 4;
    int t = lane & 15;
    int h = (w & 3) * 4 + g;
    int n = (w >> 2) & (NSEQ - 1);
    int b = w >> 13;

    int row0 = (b * NSEQ + n) * HSTRIDE;               // self leaf / Q / out
    int row1 = (b * NSEQ + (n ^ 1)) * HSTRIDE;         // sibling leaf
    int rowt[10];
#pragma unroll
    for (int l = 2; l < 12; ++l) {
        int j = l - 1;
        int slot = level_offset(j) - NSEQ + ((n >> j) ^ 1);
        rowt[l - 2] = (b * WSSLOTS + slot) * HSTRIDE;
    }
    int hoff = h * ROWF4 + t;

    // column l active iff l==0 or bit (l-1) of n set (wave-uniform)
    unsigned active = 1u | (((unsigned)n & 0x7FFu) << 1);

    float4 q4 = Q4[row0 + hoff];
    q4.x *= SCALE; q4.y *= SCALE; q4.z *= SCALE; q4.w *= SCALE;

    float4 k0 = K4[row0 + hoff];
    float4 v0 = V4[row0 + hoff];
    float4 k1, v1;
    if (active & 2u) { k1 = K4[row1 + hoff]; v1 = V4[row1 + hoff]; }
    uint4 kv[10];
#pragma unroll
    for (int l = 2; l < 12; ++l)
        if (active & (1u << l)) kv[l - 2] = KVw[rowt[l - 2] + hoff];

    float s[12];
    s[0] = dot4(q4, k0);
    s[1] = (active & 2u) ? dot4(q4, k1) : 0.f;
#pragma unroll
    for (int l = 2; l < 12; ++l)
        s[l] = (active & (1u << l)) ? dot4(q4, unpackK(kv[l - 2])) : 0.f;

#pragma unroll
    for (int m = 1; m < 16; m <<= 1) {
#pragma unroll
        for (int l = 0; l < 12; ++l) s[l] += __shfl_xor(s[l], m, 64);
    }

    float mx = -3.402823466e+38f;
#pragma unroll
    for (int l = 0; l < 12; ++l)
        if (active & (1u << l)) mx = fmaxf(mx, s[l]);
    float sum = 0.f;
#pragma unroll
    for (int l = 0; l < 12; ++l) {
        float e = (active & (1u << l)) ? __expf(s[l] - mx) : 0.f;
        s[l] = e;
        sum += e;
    }
    float inv = 1.0f / sum;

    float4 o = make_float4(0.f, 0.f, 0.f, 0.f);
    o.x += s[0] * v0.x; o.y += s[0] * v0.y;
    o.z += s[0] * v0.z; o.w += s[0] * v0.w;
    if (active & 2u) {
        o.x += s[1] * v1.x; o.y += s[1] * v1.y;
        o.z += s[1] * v1.z; o.w += s[1] * v1.w;
    }
#pragma unroll
    for (int l = 2; l < 12; ++l) {
        if (active & (1u << l)) {
            float4 vv = unpackV(kv[l - 2]);
            o.x += s[l] * vv.x; o.y += s[l] * vv.y;
            o.z += s[l] * vv.z; o.w += s[l] * vv.w;
        }
    }
    O4[row0 + hoff] = make_float4(o.x * inv, o.y * inv, o.z * inv, o.w * inv);
}

extern "C" void kernel_launch(void* const* d_in, const int* in_sizes, int n_in,
                              void* d_out, int out_size, void* d_ws, size_t ws_size,
                              hipStream_t stream) {
    const float* Q = (const float*)d_in[0];
    const float* K = (const float*)d_in[1];
    const float* V = (const float*)d_in[2];
    float* out = (float*)d_out;
    uint4* KVw = (uint4*)d_ws;                         // combined bf16 KV, 16.78 MB
    float* Kw6 = (float*)((char*)d_ws + KVBYTES);      // fp32 lvl6 stash, 262 KB
    float* Vw6 = Kw6 + (size_t)BATCH * 32 * HEADS * DIM;

    tree_low<<<1024, 256, 0, stream>>>(K, V, KVw, Kw6, Vw6);
    tree_top<<<BATCH * HEADS, 256, 0, stream>>>(KVw, Kw6, Vw6);
    attn<<<(BATCH * NSEQ * (HEADS / 4)) / 4, 256, 0, stream>>>(Q, K, V, KVw, out);
}